// Round 1
// baseline (109.450 us; speedup 1.0000x reference)
//
#include <hip/hip_runtime.h>
#include <float.h>

// Chamfer L2 loss: B=4, N=M=8192, fp32 in, scalar fp32 out.
// d(q,p) = |q|^2 + |p|^2 - 2 q.p ; track s = q.p - 0.5|p|^2 (3 fma + 1 max
// per pair), min d = |q|^2 - 2*max(s).

#define BLK 256
#define CHUNK 2048          // DB points staged in LDS per block (32 KB float4)
#define QPT 2               // queries per thread
#define QPB (BLK * QPT)     // 512 queries per block
#define B 4
#define NPTS 8192
#define TOTQ (2 * B * NPTS) // 65536 query slots (both directions)

__global__ __launch_bounds__(BLK) void init_kernel(unsigned* mins, float* out, int n) {
    int i = blockIdx.x * BLK + threadIdx.x;
    if (i < n) mins[i] = 0x7F7FFFFFu;  // FLT_MAX bit pattern
    if (i == 0) out[0] = 0.f;
}

__global__ __launch_bounds__(BLK) void zero_out_kernel(float* out) {
    if (threadIdx.x == 0 && blockIdx.x == 0) out[0] = 0.f;
}

// Main kernel: grid = 2 dir * 4 batch * 16 qtiles * 4 mchunks = 512 blocks.
__global__ __launch_bounds__(BLK, 2) void cd_chunk_kernel(
    const float* __restrict__ p1, const float* __restrict__ p2,
    unsigned* __restrict__ mins)
{
    __shared__ float4 pts[CHUNK];
    int bid    = blockIdx.x;
    int mchunk = bid & 3;
    int qt     = (bid >> 2) & 15;
    int batch  = (bid >> 6) & 3;
    int dir    = bid >> 8;

    const float* qbase = (dir == 0 ? p1 : p2) + (size_t)batch * NPTS * 3;
    const float* dbase = (dir == 0 ? p2 : p1) + (size_t)batch * NPTS * 3;

    int tid = threadIdx.x;
    int mstart = mchunk * CHUNK;
    for (int j = tid; j < CHUNK; j += BLK) {
        const float* s = dbase + (size_t)(mstart + j) * 3;
        float x = s[0], y = s[1], z = s[2];
        pts[j] = make_float4(x, y, z, -0.5f * (x * x + y * y + z * z));
    }

    int q0 = qt * QPB + tid;
    int q1 = q0 + BLK;
    float ax = qbase[q0 * 3 + 0], ay = qbase[q0 * 3 + 1], az = qbase[q0 * 3 + 2];
    float bx = qbase[q1 * 3 + 0], by = qbase[q1 * 3 + 1], bz = qbase[q1 * 3 + 2];
    float an = ax * ax + ay * ay + az * az;
    float bn = bx * bx + by * by + bz * bz;
    __syncthreads();

    float sa0 = -FLT_MAX, sa1 = -FLT_MAX;
    float sb0 = -FLT_MAX, sb1 = -FLT_MAX;
    #pragma unroll 4
    for (int j = 0; j < CHUNK; j += 2) {
        float4 u = pts[j];
        float4 v = pts[j + 1];
        float s;
        s = fmaf(ax, u.x, u.w); s = fmaf(ay, u.y, s); s = fmaf(az, u.z, s); sa0 = fmaxf(sa0, s);
        s = fmaf(bx, u.x, u.w); s = fmaf(by, u.y, s); s = fmaf(bz, u.z, s); sb0 = fmaxf(sb0, s);
        s = fmaf(ax, v.x, v.w); s = fmaf(ay, v.y, s); s = fmaf(az, v.z, s); sa1 = fmaxf(sa1, s);
        s = fmaf(bx, v.x, v.w); s = fmaf(by, v.y, s); s = fmaf(bz, v.z, s); sb1 = fmaxf(sb1, s);
    }
    float da = fmaxf(an - 2.f * fmaxf(sa0, sa1), 0.f);
    float db = fmaxf(bn - 2.f * fmaxf(sb0, sb1), 0.f);

    unsigned qid0 = (unsigned)(dir * (B * NPTS) + batch * NPTS + q0);
    atomicMin(&mins[qid0], __float_as_uint(da));
    atomicMin(&mins[qid0 + BLK], __float_as_uint(db));
}

__global__ __launch_bounds__(BLK) void sum_kernel(
    const unsigned* __restrict__ mins, float* __restrict__ out, int n, float scale)
{
    int i = blockIdx.x * BLK + threadIdx.x;
    int stride = gridDim.x * BLK;
    float v = 0.f;
    for (int idx = i; idx < n; idx += stride) v += __uint_as_float(mins[idx]);
    for (int off = 32; off > 0; off >>= 1) v += __shfl_down(v, off, 64);
    __shared__ float wsum[BLK / 64];
    int lane = threadIdx.x & 63, wid = threadIdx.x >> 6;
    if (lane == 0) wsum[wid] = v;
    __syncthreads();
    if (threadIdx.x == 0) {
        float t = 0.f;
        for (int w = 0; w < BLK / 64; ++w) t += wsum[w];
        atomicAdd(out, t * scale);
    }
}

// Fallback (no workspace needed): each block scans the whole DB in 4 LDS
// passes; block-reduces its 512 clamped mins and atomicAdds scaled sum.
__global__ __launch_bounds__(BLK) void cd_full_kernel(
    const float* __restrict__ p1, const float* __restrict__ p2,
    float* __restrict__ out)
{
    __shared__ float4 pts[CHUNK];
    int bid   = blockIdx.x;       // 0..127
    int qt    = bid & 15;
    int batch = (bid >> 4) & 3;
    int dir   = bid >> 6;

    const float* qbase = (dir == 0 ? p1 : p2) + (size_t)batch * NPTS * 3;
    const float* dbase = (dir == 0 ? p2 : p1) + (size_t)batch * NPTS * 3;

    int tid = threadIdx.x;
    int q0 = qt * QPB + tid;
    int q1 = q0 + BLK;
    float ax = qbase[q0 * 3 + 0], ay = qbase[q0 * 3 + 1], az = qbase[q0 * 3 + 2];
    float bx = qbase[q1 * 3 + 0], by = qbase[q1 * 3 + 1], bz = qbase[q1 * 3 + 2];
    float an = ax * ax + ay * ay + az * az;
    float bn = bx * bx + by * by + bz * bz;

    float sa = -FLT_MAX, sb = -FLT_MAX;
    for (int c = 0; c < 4; ++c) {
        __syncthreads();
        int mstart = c * CHUNK;
        for (int j = tid; j < CHUNK; j += BLK) {
            const float* s = dbase + (size_t)(mstart + j) * 3;
            float x = s[0], y = s[1], z = s[2];
            pts[j] = make_float4(x, y, z, -0.5f * (x * x + y * y + z * z));
        }
        __syncthreads();
        #pragma unroll 4
        for (int j = 0; j < CHUNK; j += 2) {
            float4 u = pts[j];
            float4 v = pts[j + 1];
            float s;
            s = fmaf(ax, u.x, u.w); s = fmaf(ay, u.y, s); s = fmaf(az, u.z, s); sa = fmaxf(sa, s);
            s = fmaf(bx, u.x, u.w); s = fmaf(by, u.y, s); s = fmaf(bz, u.z, s); sb = fmaxf(sb, s);
            s = fmaf(ax, v.x, v.w); s = fmaf(ay, v.y, s); s = fmaf(az, v.z, s); sa = fmaxf(sa, s);
            s = fmaf(bx, v.x, v.w); s = fmaf(by, v.y, s); s = fmaf(bz, v.z, s); sb = fmaxf(sb, s);
        }
    }
    float da = fmaxf(an - 2.f * sa, 0.f);
    float db = fmaxf(bn - 2.f * sb, 0.f);
    float v = da + db;
    for (int off = 32; off > 0; off >>= 1) v += __shfl_down(v, off, 64);
    __shared__ float wsum[BLK / 64];
    int lane = threadIdx.x & 63, wid = threadIdx.x >> 6;
    if (lane == 0) wsum[wid] = v;
    __syncthreads();
    if (threadIdx.x == 0) {
        float t = 0.f;
        for (int w = 0; w < BLK / 64; ++w) t += wsum[w];
        atomicAdd(out, t * (1.f / (float)(B * NPTS)));
    }
}

extern "C" void kernel_launch(void* const* d_in, const int* in_sizes, int n_in,
                              void* d_out, int out_size, void* d_ws, size_t ws_size,
                              hipStream_t stream) {
    const float* p1 = (const float*)d_in[0];
    const float* p2 = (const float*)d_in[1];
    float* out = (float*)d_out;

    if (ws_size >= (size_t)TOTQ * sizeof(unsigned)) {
        unsigned* mins = (unsigned*)d_ws;
        init_kernel<<<(TOTQ + BLK - 1) / BLK, BLK, 0, stream>>>(mins, out, TOTQ);
        cd_chunk_kernel<<<512, BLK, 0, stream>>>(p1, p2, mins);
        sum_kernel<<<64, BLK, 0, stream>>>(mins, out, TOTQ, 1.f / (float)(B * NPTS));
    } else {
        zero_out_kernel<<<1, BLK, 0, stream>>>(out);
        cd_full_kernel<<<128, BLK, 0, stream>>>(p1, p2, out);
    }
}